// Round 1
// baseline (1170.830 us; speedup 1.0000x reference)
//
#include <hip/hip_runtime.h>

// Problem constants: B=1, S=4096, E=768, H=12, D=64
#define SS 4096
#define EE 768
#define HH 12
#define DD 64

// ---------------- GEMM: Y[m][n] = sum_k X[m][k] * W[n][k]  (x @ W^T) -------
// M=4096, N=768, K=768. Tile 64x64, BK=32, 256 threads, 4x4 register tile.
constexpr int BM = 64, BN = 64, BK = 32;

__device__ __forceinline__ void gemm_xwt_body(const float* __restrict__ X,
                                              const float* __restrict__ W,
                                              float* __restrict__ Y) {
    // Transposed LDS tiles: Xs[k][m], Ws[k][n]; pad +4 keeps rows 16B-aligned.
    __shared__ float Xs[BK][BM + 4];
    __shared__ float Ws[BK][BN + 4];

    const int tid = threadIdx.x;
    const int m0 = blockIdx.y * BM;
    const int n0 = blockIdx.x * BN;
    const int tx = tid & 15;        // 0..15 -> n sub-tile
    const int ty = tid >> 4;        // 0..15 -> m sub-tile
    const int lrow = tid >> 3;      // 0..31 (row within tile for loads)
    const int lk = (tid & 7) * 4;   // k offset for float4 load

    float acc[4][4] = {};

    for (int k0 = 0; k0 < EE; k0 += BK) {
        __syncthreads();
#pragma unroll
        for (int rr = 0; rr < 2; ++rr) {
            const int r = lrow + rr * 32;
            const float4 xv = *(const float4*)(X + (size_t)(m0 + r) * EE + k0 + lk);
            Xs[lk + 0][r] = xv.x; Xs[lk + 1][r] = xv.y;
            Xs[lk + 2][r] = xv.z; Xs[lk + 3][r] = xv.w;
            const float4 wv = *(const float4*)(W + (size_t)(n0 + r) * EE + k0 + lk);
            Ws[lk + 0][r] = wv.x; Ws[lk + 1][r] = wv.y;
            Ws[lk + 2][r] = wv.z; Ws[lk + 3][r] = wv.w;
        }
        __syncthreads();
#pragma unroll
        for (int kk = 0; kk < BK; ++kk) {
            const float4 a = *(const float4*)&Xs[kk][ty * 4];
            const float4 b = *(const float4*)&Ws[kk][tx * 4];
            const float av[4] = {a.x, a.y, a.z, a.w};
            const float bv[4] = {b.x, b.y, b.z, b.w};
#pragma unroll
            for (int i = 0; i < 4; ++i)
#pragma unroll
                for (int j = 0; j < 4; ++j)
                    acc[i][j] += av[i] * bv[j];
        }
    }

#pragma unroll
    for (int i = 0; i < 4; ++i) {
        const float4 o = make_float4(acc[i][0], acc[i][1], acc[i][2], acc[i][3]);
        *(float4*)(Y + (size_t)(m0 + ty * 4 + i) * EE + n0 + tx * 4) = o;
    }
}

__global__ __launch_bounds__(256) void qkv_proj_kernel(
    const float* __restrict__ Xq, const float* __restrict__ Xk,
    const float* __restrict__ Xv, const float* __restrict__ Wq,
    const float* __restrict__ Wk, const float* __restrict__ Wv,
    float* __restrict__ Yq, float* __restrict__ Yk, float* __restrict__ Yv) {
    const int z = blockIdx.z;
    const float* X = (z == 0) ? Xq : (z == 1) ? Xk : Xv;
    const float* W = (z == 0) ? Wq : (z == 1) ? Wk : Wv;
    float* Y = (z == 0) ? Yq : (z == 1) ? Yk : Yv;
    gemm_xwt_body(X, W, Y);
}

__global__ __launch_bounds__(256) void out_proj_kernel(
    const float* __restrict__ X, const float* __restrict__ W,
    float* __restrict__ Y) {
    gemm_xwt_body(X, W, Y);
}

// ---------------- Flash attention (fp32) -----------------------------------
// One block = one head x 64 query rows. 256 threads as 16x16: thread (ty,tx)
// owns q-rows 4*ty..+3 and (score-cols / d-cols) 4*tx..+3.
__global__ __launch_bounds__(256) void attn_kernel(const float* __restrict__ Q,
                                                   const float* __restrict__ K,
                                                   const float* __restrict__ V,
                                                   float* __restrict__ C) {
    __shared__ float Qt[DD][64 + 4];   // Qt[d][r], pre-scaled by 1/sqrt(D)
    __shared__ float Kt[DD][64 + 4];   // Kt[d][c]
    __shared__ float Vs[64][DD + 4];   // Vs[k][d]
    __shared__ float Pt[64][64 + 4];   // Pt[c][r]

    const int tid = threadIdx.x;
    const int h = blockIdx.y;
    const int qm0 = blockIdx.x * 64;
    const int tx = tid & 15;
    const int ty = tid >> 4;
    const int lr = tid >> 4;          // 0..15 row for loads
    const int ld = (tid & 15) * 4;    // d offset for float4 load
    const float scale = 0.125f;       // 1/sqrt(64)

    // Load Q tile transposed, pre-scaled
#pragma unroll
    for (int p = 0; p < 4; ++p) {
        const int r = lr + p * 16;
        const float4 x = *(const float4*)(Q + (size_t)(qm0 + r) * EE + h * DD + ld);
        Qt[ld + 0][r] = x.x * scale; Qt[ld + 1][r] = x.y * scale;
        Qt[ld + 2][r] = x.z * scale; Qt[ld + 3][r] = x.w * scale;
    }

    float o[4][4] = {};
    float m_i[4], l_i[4];
#pragma unroll
    for (int i = 0; i < 4; ++i) { m_i[i] = -1e30f; l_i[i] = 0.0f; }

    for (int t0 = 0; t0 < SS; t0 += 64) {
        __syncthreads();  // prior PV reads of Kt/Vs/Pt complete
#pragma unroll
        for (int p = 0; p < 4; ++p) {
            const int r = lr + p * 16;
            const float4 kv = *(const float4*)(K + (size_t)(t0 + r) * EE + h * DD + ld);
            Kt[ld + 0][r] = kv.x; Kt[ld + 1][r] = kv.y;
            Kt[ld + 2][r] = kv.z; Kt[ld + 3][r] = kv.w;
            const float4 vv = *(const float4*)(V + (size_t)(t0 + r) * EE + h * DD + ld);
            Vs[r][ld + 0] = vv.x; Vs[r][ld + 1] = vv.y;
            Vs[r][ld + 2] = vv.z; Vs[r][ld + 3] = vv.w;
        }
        __syncthreads();

        // S-tile: sc[i][j] = sum_d Qt[d][4ty+i] * Kt[d][4tx+j]
        float sc[4][4] = {};
#pragma unroll 8
        for (int d = 0; d < DD; ++d) {
            const float4 a = *(const float4*)&Qt[d][ty * 4];
            const float4 b = *(const float4*)&Kt[d][tx * 4];
            const float av[4] = {a.x, a.y, a.z, a.w};
            const float bv[4] = {b.x, b.y, b.z, b.w};
#pragma unroll
            for (int i = 0; i < 4; ++i)
#pragma unroll
                for (int j = 0; j < 4; ++j)
                    sc[i][j] += av[i] * bv[j];
        }

        // Online softmax (16 lanes per row-group share the same 4 rows)
#pragma unroll
        for (int i = 0; i < 4; ++i) {
            float mx = fmaxf(fmaxf(sc[i][0], sc[i][1]), fmaxf(sc[i][2], sc[i][3]));
#pragma unroll
            for (int off = 8; off > 0; off >>= 1)
                mx = fmaxf(mx, __shfl_xor(mx, off, 16));
            const float mnew = fmaxf(m_i[i], mx);
            const float corr = __expf(m_i[i] - mnew);
            m_i[i] = mnew;
            float rs = 0.0f;
#pragma unroll
            for (int j = 0; j < 4; ++j) {
                sc[i][j] = __expf(sc[i][j] - mnew);
                rs += sc[i][j];
            }
#pragma unroll
            for (int off = 8; off > 0; off >>= 1)
                rs += __shfl_xor(rs, off, 16);
            l_i[i] = l_i[i] * corr + rs;
#pragma unroll
            for (int j = 0; j < 4; ++j) o[i][j] *= corr;
        }

        // Write P transposed for the PV loop
#pragma unroll
        for (int i = 0; i < 4; ++i)
#pragma unroll
            for (int j = 0; j < 4; ++j)
                Pt[tx * 4 + j][ty * 4 + i] = sc[i][j];
        __syncthreads();

        // PV: o[i][j] += sum_k Pt[k][4ty+i] * Vs[k][4tx+j]
#pragma unroll 8
        for (int k = 0; k < 64; ++k) {
            const float4 a = *(const float4*)&Pt[k][ty * 4];
            const float4 b = *(const float4*)&Vs[k][tx * 4];
            const float av[4] = {a.x, a.y, a.z, a.w};
            const float bv[4] = {b.x, b.y, b.z, b.w};
#pragma unroll
            for (int i = 0; i < 4; ++i)
#pragma unroll
                for (int j = 0; j < 4; ++j)
                    o[i][j] += av[i] * bv[j];
        }
    }

    // Normalize and store ctx[(qm0+r)][h*64 + d]
#pragma unroll
    for (int i = 0; i < 4; ++i) {
        const float inv = 1.0f / l_i[i];
        const float4 out = make_float4(o[i][0] * inv, o[i][1] * inv,
                                       o[i][2] * inv, o[i][3] * inv);
        *(float4*)(C + (size_t)(qm0 + ty * 4 + i) * EE + h * DD + tx * 4) = out;
    }
}

// ---------------- launch ----------------------------------------------------
extern "C" void kernel_launch(void* const* d_in, const int* in_sizes, int n_in,
                              void* d_out, int out_size, void* d_ws, size_t ws_size,
                              hipStream_t stream) {
    const float* inQ = (const float*)d_in[0];
    const float* inK = (const float*)d_in[1];
    const float* inV = (const float*)d_in[2];
    const float* Wq = (const float*)d_in[3];
    const float* Wk = (const float*)d_in[4];
    const float* Wv = (const float*)d_in[5];
    const float* Wo = (const float*)d_in[6];
    float* out = (float*)d_out;

    float* q = (float*)d_ws;                 // [S,E]
    float* k = q + (size_t)SS * EE;          // [S,E]
    float* v = k + (size_t)SS * EE;          // [S,E]
    float* c = v + (size_t)SS * EE;          // [S,E]

    // QKV projections: grid (N/BN, M/BM, 3)
    qkv_proj_kernel<<<dim3(EE / BN, SS / BM, 3), dim3(256), 0, stream>>>(
        inQ, inK, inV, Wq, Wk, Wv, q, k, v);

    // Attention: grid (S/64 q-tiles, H heads)
    attn_kernel<<<dim3(SS / 64, HH), dim3(256), 0, stream>>>(q, k, v, c);

    // Output projection
    out_proj_kernel<<<dim3(EE / BN, SS / BM), dim3(256), 0, stream>>>(c, Wo, out);
}

// Round 2
// 537.555 us; speedup vs baseline: 2.1781x; 2.1781x over previous
//
#include <hip/hip_runtime.h>

// Problem constants: B=1, S=4096, E=768, H=12, D=64
#define SS 4096
#define EE 768
#define HH 12
#define DD 64

typedef __attribute__((ext_vector_type(4))) float f32x4;
typedef __attribute__((ext_vector_type(8))) _Float16 f16x8;
typedef __attribute__((ext_vector_type(4))) _Float16 f16x4;
typedef __attribute__((ext_vector_type(8))) unsigned short u16x8;

// ---------------- GEMM: Y[m][n] = sum_k X[m][k] * W[n][k]  (x @ W^T) -------
// M=4096, N=768, K=768. Tile 64x64, BK=32, 256 threads, 4x4 register tile.
constexpr int BM = 64, BN = 64, BK = 32;

template <bool F16OUT>
__device__ __forceinline__ void gemm_xwt_body(const float* __restrict__ X,
                                              const float* __restrict__ W,
                                              void* __restrict__ Yv,
                                              float oscale) {
    __shared__ float Xs[BK][BM + 4];
    __shared__ float Ws[BK][BN + 4];

    const int tid = threadIdx.x;
    const int m0 = blockIdx.y * BM;
    const int n0 = blockIdx.x * BN;
    const int tx = tid & 15;
    const int ty = tid >> 4;
    const int lrow = tid >> 3;
    const int lk = (tid & 7) * 4;

    float acc[4][4] = {};

    for (int k0 = 0; k0 < EE; k0 += BK) {
        __syncthreads();
#pragma unroll
        for (int rr = 0; rr < 2; ++rr) {
            const int r = lrow + rr * 32;
            const float4 xv = *(const float4*)(X + (size_t)(m0 + r) * EE + k0 + lk);
            Xs[lk + 0][r] = xv.x; Xs[lk + 1][r] = xv.y;
            Xs[lk + 2][r] = xv.z; Xs[lk + 3][r] = xv.w;
            const float4 wv = *(const float4*)(W + (size_t)(n0 + r) * EE + k0 + lk);
            Ws[lk + 0][r] = wv.x; Ws[lk + 1][r] = wv.y;
            Ws[lk + 2][r] = wv.z; Ws[lk + 3][r] = wv.w;
        }
        __syncthreads();
#pragma unroll
        for (int kk = 0; kk < BK; ++kk) {
            const float4 a = *(const float4*)&Xs[kk][ty * 4];
            const float4 b = *(const float4*)&Ws[kk][tx * 4];
            const float av[4] = {a.x, a.y, a.z, a.w};
            const float bv[4] = {b.x, b.y, b.z, b.w};
#pragma unroll
            for (int i = 0; i < 4; ++i)
#pragma unroll
                for (int j = 0; j < 4; ++j)
                    acc[i][j] += av[i] * bv[j];
        }
    }

    if (F16OUT) {
        _Float16* Y = (_Float16*)Yv;
#pragma unroll
        for (int i = 0; i < 4; ++i) {
            f16x4 ov;
            ov[0] = (_Float16)(acc[i][0] * oscale);
            ov[1] = (_Float16)(acc[i][1] * oscale);
            ov[2] = (_Float16)(acc[i][2] * oscale);
            ov[3] = (_Float16)(acc[i][3] * oscale);
            *(f16x4*)(Y + (size_t)(m0 + ty * 4 + i) * EE + n0 + tx * 4) = ov;
        }
    } else {
        float* Y = (float*)Yv;
#pragma unroll
        for (int i = 0; i < 4; ++i) {
            const float4 o = make_float4(acc[i][0], acc[i][1], acc[i][2], acc[i][3]);
            *(float4*)(Y + (size_t)(m0 + ty * 4 + i) * EE + n0 + tx * 4) = o;
        }
    }
}

// QKV projections with f16 epilogue (Q pre-scaled by 1/sqrt(D))
__global__ __launch_bounds__(256) void qkv_proj_kernel(
    const float* __restrict__ Xq, const float* __restrict__ Xk,
    const float* __restrict__ Xv, const float* __restrict__ Wq,
    const float* __restrict__ Wk, const float* __restrict__ Wv,
    _Float16* __restrict__ Yq, _Float16* __restrict__ Yk,
    _Float16* __restrict__ Yv) {
    const int z = blockIdx.z;
    const float* X = (z == 0) ? Xq : (z == 1) ? Xk : Xv;
    const float* W = (z == 0) ? Wq : (z == 1) ? Wk : Wv;
    _Float16* Y = (z == 0) ? Yq : (z == 1) ? Yk : Yv;
    const float oscale = (z == 0) ? 0.125f : 1.0f;  // 1/sqrt(64) folded into Q
    gemm_xwt_body<true>(X, W, (void*)Y, oscale);
}

__global__ __launch_bounds__(256) void out_proj_kernel(
    const float* __restrict__ X, const float* __restrict__ W,
    float* __restrict__ Y) {
    gemm_xwt_body<false>(X, W, (void*)Y, 1.0f);
}

// ---------------- Flash attention, f16 MFMA ---------------------------------
// Block: 256 threads = 4 waves; 64 q-rows per block, one head.
// Wave w owns q-rows [q0+16w, q0+16w+16). KV tiles of 64 rows.
// MFMA 16x16x32_f16 layouts (m89/m91-verified):
//   A[m][k]: a[j] = A[lane&15][(lane>>4)*8 + j]
//   B[k][n]: b[j] = B[(lane>>4)*8 + j][lane&15]
//   D[m][n]: d[r] = D[(lane>>4)*4 + r][lane&15]
__global__ __launch_bounds__(256) void attn_mfma_kernel(
    const _Float16* __restrict__ Qf, const _Float16* __restrict__ Kf,
    const _Float16* __restrict__ Vf, float* __restrict__ C) {
    __shared__ _Float16 Ks[64][72];           // K[kv][d], row stride 144 B
    __shared__ unsigned char VtB[64 * 144];   // Vt[d][kv] f16, XOR-swizzled
    __shared__ _Float16 Ps[4][16][72];        // per-wave P[q][kv]

    const int tid = threadIdx.x;
    // XCD-aware bijective swizzle: 768 blocks = 8 XCDs x 96 -> each XCD
    // handles a contiguous sw-range (<=2 heads -> K/V slices L2-resident).
    const int bid = blockIdx.x;
    const int sw = (bid & 7) * 96 + (bid >> 3);
    const int h = sw >> 6;           // head 0..11
    const int q0 = (sw & 63) * 64;   // q-tile base
    const int w = tid >> 6;
    const int lane = tid & 63;
    const int g = lane >> 4;
    const int c = lane & 15;

    // staging assignments
    const int kr = tid >> 3;        // 0..31 (K rows kr, kr+32)
    const int kc = tid & 7;         // 16B chunk within row
    const int vr = tid >> 3;        // 0..31 -> V row pair (2vr, 2vr+1)
    const int vm = tid & 7;         // d0 = vm*8

    // Q A-frags, hoisted (Q pre-scaled by 1/sqrt(D) at projection)
    f16x8 qa[2];
    {
        const _Float16* qp = Qf + (size_t)(q0 + w * 16 + c) * EE + h * DD + g * 8;
        qa[0] = *(const f16x8*)(qp);
        qa[1] = *(const f16x8*)(qp + 32);
    }

    f32x4 o[4] = {};   // o[nt][r]
    float m_r[4], l_r[4];
#pragma unroll
    for (int r = 0; r < 4; ++r) { m_r[r] = -1e30f; l_r[r] = 0.0f; }

    for (int t0 = 0; t0 < SS; t0 += 64) {
        __syncthreads();  // previous tile's LDS reads complete
        // --- stage K (row-major) ---
        {
            const _Float16* kp = Kf + (size_t)(t0 + kr) * EE + h * DD + kc * 8;
            *(f16x8*)(&Ks[kr][kc * 8]) = *(const f16x8*)(kp);
            *(f16x8*)(&Ks[kr + 32][kc * 8]) = *(const f16x8*)(kp + (size_t)32 * EE);
        }
        // --- stage V transposed (Vt[d][kv]), packed u32 (2 kv per write) ---
        {
            const unsigned short* vp =
                (const unsigned short*)(Vf + (size_t)(t0 + 2 * vr) * EE + h * DD + vm * 8);
            u16x8 va = *(const u16x8*)(vp);
            u16x8 vb = *(const u16x8*)(vp + EE);
#pragma unroll
            for (int j = 0; j < 8; ++j) {
                const int d = vm * 8 + j;
                const unsigned off =
                    (unsigned)(144 * d + 4 * vr) ^ (unsigned)(((d >> 3) & 7) << 4);
                *(unsigned int*)(VtB + off) = ((unsigned)vb[j] << 16) | (unsigned)va[j];
            }
        }
        __syncthreads();

        // --- QK^T: S[16 q][64 kv] per wave ---
        f32x4 sc[4] = {};
#pragma unroll
        for (int ks = 0; ks < 2; ++ks) {
#pragma unroll
            for (int nt = 0; nt < 4; ++nt) {
                const f16x8 kb = *(const f16x8*)(&Ks[c + 16 * nt][ks * 32 + g * 8]);
                sc[nt] = __builtin_amdgcn_mfma_f32_16x16x32_f16(qa[ks], kb, sc[nt], 0, 0, 0);
            }
        }

        // --- online softmax (wave-parallel; lane group of 16 shares 4 rows) ---
        float corr[4];
#pragma unroll
        for (int r = 0; r < 4; ++r) {
            float mx = fmaxf(fmaxf(sc[0][r], sc[1][r]), fmaxf(sc[2][r], sc[3][r]));
            mx = fmaxf(mx, __shfl_xor(mx, 1));
            mx = fmaxf(mx, __shfl_xor(mx, 2));
            mx = fmaxf(mx, __shfl_xor(mx, 4));
            mx = fmaxf(mx, __shfl_xor(mx, 8));
            const float mnew = fmaxf(m_r[r], mx);
            corr[r] = __expf(m_r[r] - mnew);
            m_r[r] = mnew;
            const float p0 = __expf(sc[0][r] - mnew);
            const float p1 = __expf(sc[1][r] - mnew);
            const float p2 = __expf(sc[2][r] - mnew);
            const float p3 = __expf(sc[3][r] - mnew);
            float rs = p0 + p1 + p2 + p3;
            rs += __shfl_xor(rs, 1);
            rs += __shfl_xor(rs, 2);
            rs += __shfl_xor(rs, 4);
            rs += __shfl_xor(rs, 8);
            l_r[r] = l_r[r] * corr[r] + rs;
            Ps[w][4 * g + r][c + 0]  = (_Float16)p0;
            Ps[w][4 * g + r][c + 16] = (_Float16)p1;
            Ps[w][4 * g + r][c + 32] = (_Float16)p2;
            Ps[w][4 * g + r][c + 48] = (_Float16)p3;
        }
#pragma unroll
        for (int nt = 0; nt < 4; ++nt)
#pragma unroll
            for (int r = 0; r < 4; ++r)
                o[nt][r] *= corr[r];

        // --- PV: O[16 q][64 d] += P[16 q][64 kv] * V[64 kv][64 d] ---
        // (wave-private Ps write->read: LDS ops from one wave complete in order)
#pragma unroll
        for (int ks = 0; ks < 2; ++ks) {
            const f16x8 pa = *(const f16x8*)(&Ps[w][c][ks * 32 + g * 8]);
#pragma unroll
            for (int nt = 0; nt < 4; ++nt) {
                const int d = nt * 16 + c;
                const unsigned off =
                    (unsigned)(144 * d + 64 * ks + 16 * g) ^
                    (unsigned)(((d >> 3) & 7) << 4);
                const f16x8 vbf = *(const f16x8*)(VtB + off);
                o[nt] = __builtin_amdgcn_mfma_f32_16x16x32_f16(pa, vbf, o[nt], 0, 0, 0);
            }
        }
    }

    // --- epilogue: normalize, store ctx fp32 ---
    float inv[4];
#pragma unroll
    for (int r = 0; r < 4; ++r) inv[r] = 1.0f / l_r[r];
#pragma unroll
    for (int nt = 0; nt < 4; ++nt)
#pragma unroll
        for (int r = 0; r < 4; ++r)
            C[(size_t)(q0 + w * 16 + 4 * g + r) * EE + h * DD + nt * 16 + c] =
                o[nt][r] * inv[r];
}

// ---------------- launch ----------------------------------------------------
extern "C" void kernel_launch(void* const* d_in, const int* in_sizes, int n_in,
                              void* d_out, int out_size, void* d_ws, size_t ws_size,
                              hipStream_t stream) {
    const float* inQ = (const float*)d_in[0];
    const float* inK = (const float*)d_in[1];
    const float* inV = (const float*)d_in[2];
    const float* Wq = (const float*)d_in[3];
    const float* Wk = (const float*)d_in[4];
    const float* Wv = (const float*)d_in[5];
    const float* Wo = (const float*)d_in[6];
    float* out = (float*)d_out;

    _Float16* Qf = (_Float16*)d_ws;              // [S,E] f16 (pre-scaled)
    _Float16* Kf = Qf + (size_t)SS * EE;         // [S,E] f16
    _Float16* Vf = Kf + (size_t)SS * EE;         // [S,E] f16
    float* ctx = (float*)(Vf + (size_t)SS * EE); // [S,E] fp32

    qkv_proj_kernel<<<dim3(EE / BN, SS / BM, 3), dim3(256), 0, stream>>>(
        inQ, inK, inV, Wq, Wk, Wv, Qf, Kf, Vf);

    attn_mfma_kernel<<<dim3((SS / 64) * HH), dim3(256), 0, stream>>>(Qf, Kf, Vf, ctx);

    out_proj_kernel<<<dim3(EE / BN, SS / BM), dim3(256), 0, stream>>>(ctx, Wo, out);
}

// Round 3
// 327.419 us; speedup vs baseline: 3.5759x; 1.6418x over previous
//
#include <hip/hip_runtime.h>

// Problem constants: B=1, S=4096, E=768, H=12, D=64
#define SS 4096
#define EE 768
#define HH 12
#define DD 64

typedef __attribute__((ext_vector_type(4))) float f32x4;
typedef __attribute__((ext_vector_type(8))) _Float16 f16x8;
typedef __attribute__((ext_vector_type(4))) _Float16 f16x4;
typedef __attribute__((ext_vector_type(8))) unsigned short u16x8;

// ---------------- cast fp32 -> f16 (Wq pre-scaled by 1/sqrt(D)) ------------
__global__ __launch_bounds__(256) void cast_kernel(
    const float* __restrict__ xq, const float* __restrict__ xk,
    const float* __restrict__ xv, const float* __restrict__ wq,
    const float* __restrict__ wk, const float* __restrict__ wv,
    const float* __restrict__ wo, _Float16* __restrict__ oxq,
    _Float16* __restrict__ oxk, _Float16* __restrict__ oxv,
    _Float16* __restrict__ owq, _Float16* __restrict__ owk,
    _Float16* __restrict__ owv, _Float16* __restrict__ owo) {
    const int seg = blockIdx.y;
    const float* src;
    _Float16* dst;
    int n;
    float s = 1.0f;
    switch (seg) {
        case 0: src = xq; dst = oxq; n = SS * EE; break;
        case 1: src = xk; dst = oxk; n = SS * EE; break;
        case 2: src = xv; dst = oxv; n = SS * EE; break;
        case 3: src = wq; dst = owq; n = EE * EE; s = 0.125f; break;
        case 4: src = wk; dst = owk; n = EE * EE; break;
        case 5: src = wv; dst = owv; n = EE * EE; break;
        default: src = wo; dst = owo; n = EE * EE; break;
    }
    const int i = (blockIdx.x * 256 + threadIdx.x) * 4;
    if (i < n) {
        const float4 v = *(const float4*)(src + i);
        f16x4 o;
        o[0] = (_Float16)(v.x * s); o[1] = (_Float16)(v.y * s);
        o[2] = (_Float16)(v.z * s); o[3] = (_Float16)(v.w * s);
        *(f16x4*)(dst + i) = o;
    }
}

// ---------------- f16 MFMA GEMM: Y[m][n] = sum_k A[m][k] * B[n][k] ---------
// m97 structure: 128x128 tile, BK=32, 256 threads (4 waves, 2x2 of 64x64),
// global_load_lds width 16, 2 barriers per K-step.
// MFMA 16x16x32_f16 layouts (verified in round-2 attention):
//   A-frag a[j] = A[lane&15][(lane>>4)*8+j]
//   B-frag b[j] = B[(lane>>4)*8+j][lane&15]   (B[k][n] = Bt[n][k] input)
//   D d[r]      = D[(lane>>4)*4+r][lane&15]
template <bool F32OUT>
__device__ __forceinline__ void gemm_f16_body(const _Float16* __restrict__ A,
                                              const _Float16* __restrict__ B,
                                              void* __restrict__ Yv) {
    __shared__ _Float16 As[128 * 32];
    __shared__ _Float16 Bs[128 * 32];

    const int tid = threadIdx.x;
    const int w = tid >> 6, lane = tid & 63;
    const int g = lane >> 4, c = lane & 15;
    const int wr = (w >> 1) * 64, wc = (w & 1) * 64;
    const int m0 = blockIdx.y * 128, n0 = blockIdx.x * 128;

    f32x4 acc[4][4] = {};

    for (int k0 = 0; k0 < EE; k0 += 32) {
        __syncthreads();  // prior iteration's ds_reads complete
#pragma unroll
        for (int i = 0; i < 2; ++i) {
            const int ca = tid + i * 256;  // chunk: row=ca>>2, 16B col=ca&3
            __builtin_amdgcn_global_load_lds(
                (const __attribute__((address_space(1))) void*)(
                    A + (size_t)(m0 + (ca >> 2)) * EE + k0 + (ca & 3) * 8),
                (__attribute__((address_space(3))) void*)(As + ca * 8), 16, 0, 0);
            __builtin_amdgcn_global_load_lds(
                (const __attribute__((address_space(1))) void*)(
                    B + (size_t)(n0 + (ca >> 2)) * EE + k0 + (ca & 3) * 8),
                (__attribute__((address_space(3))) void*)(Bs + ca * 8), 16, 0, 0);
        }
        __syncthreads();  // drains vmcnt -> staging visible

        f16x8 af[4], bf[4];
#pragma unroll
        for (int t = 0; t < 4; ++t) {
            af[t] = *(const f16x8*)(As + (wr + t * 16 + c) * 32 + g * 8);
            bf[t] = *(const f16x8*)(Bs + (wc + t * 16 + c) * 32 + g * 8);
        }
#pragma unroll
        for (int mt = 0; mt < 4; ++mt)
#pragma unroll
            for (int nt = 0; nt < 4; ++nt)
                acc[mt][nt] = __builtin_amdgcn_mfma_f32_16x16x32_f16(
                    af[mt], bf[nt], acc[mt][nt], 0, 0, 0);
    }

    if (F32OUT) {
        float* Y = (float*)Yv;
#pragma unroll
        for (int mt = 0; mt < 4; ++mt)
#pragma unroll
            for (int nt = 0; nt < 4; ++nt)
#pragma unroll
                for (int r = 0; r < 4; ++r)
                    Y[(size_t)(m0 + wr + mt * 16 + g * 4 + r) * EE +
                      n0 + wc + nt * 16 + c] = acc[mt][nt][r];
    } else {
        _Float16* Y = (_Float16*)Yv;
#pragma unroll
        for (int mt = 0; mt < 4; ++mt)
#pragma unroll
            for (int nt = 0; nt < 4; ++nt)
#pragma unroll
                for (int r = 0; r < 4; ++r)
                    Y[(size_t)(m0 + wr + mt * 16 + g * 4 + r) * EE +
                      n0 + wc + nt * 16 + c] = (_Float16)acc[mt][nt][r];
    }
}

__global__ __launch_bounds__(256) void qkv_gemm_kernel(
    const _Float16* __restrict__ Xq, const _Float16* __restrict__ Xk,
    const _Float16* __restrict__ Xv, const _Float16* __restrict__ Wq,
    const _Float16* __restrict__ Wk, const _Float16* __restrict__ Wv,
    _Float16* __restrict__ Yq, _Float16* __restrict__ Yk,
    _Float16* __restrict__ Yv) {
    const int z = blockIdx.z;
    const _Float16* X = (z == 0) ? Xq : (z == 1) ? Xk : Xv;
    const _Float16* W = (z == 0) ? Wq : (z == 1) ? Wk : Wv;
    _Float16* Y = (z == 0) ? Yq : (z == 1) ? Yk : Yv;
    gemm_f16_body<false>(X, W, (void*)Y);
}

__global__ __launch_bounds__(256) void out_gemm_kernel(
    const _Float16* __restrict__ X, const _Float16* __restrict__ W,
    float* __restrict__ Y) {
    gemm_f16_body<true>(X, W, (void*)Y);
}

// ---------------- Flash attention, f16 MFMA (unchanged; f16 ctx out) -------
__global__ __launch_bounds__(256) void attn_mfma_kernel(
    const _Float16* __restrict__ Qf, const _Float16* __restrict__ Kf,
    const _Float16* __restrict__ Vf, _Float16* __restrict__ C) {
    __shared__ _Float16 Ks[64][72];           // K[kv][d], row stride 144 B
    __shared__ unsigned char VtB[64 * 144];   // Vt[d][kv] f16, XOR-swizzled
    __shared__ _Float16 Ps[4][16][72];        // per-wave P[q][kv]

    const int tid = threadIdx.x;
    const int bid = blockIdx.x;
    const int sw = (bid & 7) * 96 + (bid >> 3);  // XCD-aware bijective swizzle
    const int h = sw >> 6;
    const int q0 = (sw & 63) * 64;
    const int w = tid >> 6;
    const int lane = tid & 63;
    const int g = lane >> 4;
    const int c = lane & 15;

    const int kr = tid >> 3;
    const int kc = tid & 7;
    const int vr = tid >> 3;
    const int vm = tid & 7;

    f16x8 qa[2];
    {
        const _Float16* qp = Qf + (size_t)(q0 + w * 16 + c) * EE + h * DD + g * 8;
        qa[0] = *(const f16x8*)(qp);
        qa[1] = *(const f16x8*)(qp + 32);
    }

    f32x4 o[4] = {};
    float m_r[4], l_r[4];
#pragma unroll
    for (int r = 0; r < 4; ++r) { m_r[r] = -1e30f; l_r[r] = 0.0f; }

    for (int t0 = 0; t0 < SS; t0 += 64) {
        __syncthreads();
        {
            const _Float16* kp = Kf + (size_t)(t0 + kr) * EE + h * DD + kc * 8;
            *(f16x8*)(&Ks[kr][kc * 8]) = *(const f16x8*)(kp);
            *(f16x8*)(&Ks[kr + 32][kc * 8]) = *(const f16x8*)(kp + (size_t)32 * EE);
        }
        {
            const unsigned short* vp =
                (const unsigned short*)(Vf + (size_t)(t0 + 2 * vr) * EE + h * DD + vm * 8);
            u16x8 va = *(const u16x8*)(vp);
            u16x8 vb = *(const u16x8*)(vp + EE);
#pragma unroll
            for (int j = 0; j < 8; ++j) {
                const int d = vm * 8 + j;
                const unsigned off =
                    (unsigned)(144 * d + 4 * vr) ^ (unsigned)(((d >> 3) & 7) << 4);
                *(unsigned int*)(VtB + off) = ((unsigned)vb[j] << 16) | (unsigned)va[j];
            }
        }
        __syncthreads();

        f32x4 sc[4] = {};
#pragma unroll
        for (int ks = 0; ks < 2; ++ks) {
#pragma unroll
            for (int nt = 0; nt < 4; ++nt) {
                const f16x8 kb = *(const f16x8*)(&Ks[c + 16 * nt][ks * 32 + g * 8]);
                sc[nt] = __builtin_amdgcn_mfma_f32_16x16x32_f16(qa[ks], kb, sc[nt], 0, 0, 0);
            }
        }

        float corr[4];
#pragma unroll
        for (int r = 0; r < 4; ++r) {
            float mx = fmaxf(fmaxf(sc[0][r], sc[1][r]), fmaxf(sc[2][r], sc[3][r]));
            mx = fmaxf(mx, __shfl_xor(mx, 1));
            mx = fmaxf(mx, __shfl_xor(mx, 2));
            mx = fmaxf(mx, __shfl_xor(mx, 4));
            mx = fmaxf(mx, __shfl_xor(mx, 8));
            const float mnew = fmaxf(m_r[r], mx);
            corr[r] = __expf(m_r[r] - mnew);
            m_r[r] = mnew;
            const float p0 = __expf(sc[0][r] - mnew);
            const float p1 = __expf(sc[1][r] - mnew);
            const float p2 = __expf(sc[2][r] - mnew);
            const float p3 = __expf(sc[3][r] - mnew);
            float rs = p0 + p1 + p2 + p3;
            rs += __shfl_xor(rs, 1);
            rs += __shfl_xor(rs, 2);
            rs += __shfl_xor(rs, 4);
            rs += __shfl_xor(rs, 8);
            l_r[r] = l_r[r] * corr[r] + rs;
            Ps[w][4 * g + r][c + 0]  = (_Float16)p0;
            Ps[w][4 * g + r][c + 16] = (_Float16)p1;
            Ps[w][4 * g + r][c + 32] = (_Float16)p2;
            Ps[w][4 * g + r][c + 48] = (_Float16)p3;
        }
#pragma unroll
        for (int nt = 0; nt < 4; ++nt)
#pragma unroll
            for (int r = 0; r < 4; ++r)
                o[nt][r] *= corr[r];

#pragma unroll
        for (int ks = 0; ks < 2; ++ks) {
            const f16x8 pa = *(const f16x8*)(&Ps[w][c][ks * 32 + g * 8]);
#pragma unroll
            for (int nt = 0; nt < 4; ++nt) {
                const int d = nt * 16 + c;
                const unsigned off =
                    (unsigned)(144 * d + 64 * ks + 16 * g) ^
                    (unsigned)(((d >> 3) & 7) << 4);
                const f16x8 vbf = *(const f16x8*)(VtB + off);
                o[nt] = __builtin_amdgcn_mfma_f32_16x16x32_f16(pa, vbf, o[nt], 0, 0, 0);
            }
        }
    }

    float inv[4];
#pragma unroll
    for (int r = 0; r < 4; ++r) inv[r] = 1.0f / l_r[r];
#pragma unroll
    for (int nt = 0; nt < 4; ++nt)
#pragma unroll
        for (int r = 0; r < 4; ++r)
            C[(size_t)(q0 + w * 16 + 4 * g + r) * EE + h * DD + nt * 16 + c] =
                (_Float16)(o[nt][r] * inv[r]);
}

// ---------------- launch ----------------------------------------------------
extern "C" void kernel_launch(void* const* d_in, const int* in_sizes, int n_in,
                              void* d_out, int out_size, void* d_ws, size_t ws_size,
                              hipStream_t stream) {
    const float* inQ = (const float*)d_in[0];
    const float* inK = (const float*)d_in[1];
    const float* inV = (const float*)d_in[2];
    const float* Wq = (const float*)d_in[3];
    const float* Wk = (const float*)d_in[4];
    const float* Wv = (const float*)d_in[5];
    const float* Wo = (const float*)d_in[6];
    float* out = (float*)d_out;

    const size_t SE = (size_t)SS * EE, E2 = (size_t)EE * EE;
    _Float16* p = (_Float16*)d_ws;
    _Float16* X16q = p; p += SE;
    _Float16* X16k = p; p += SE;
    _Float16* X16v = p; p += SE;
    _Float16* W16q = p; p += E2;
    _Float16* W16k = p; p += E2;
    _Float16* W16v = p; p += E2;
    _Float16* W16o = p; p += E2;
    _Float16* Qf = p; p += SE;
    _Float16* Kf = p; p += SE;
    _Float16* Vf = p; p += SE;
    _Float16* ctx = p; p += SE;

    // cast: grid.x covers SS*EE/4 elems/thread-block-of-256
    cast_kernel<<<dim3(SS * EE / 1024, 7), dim3(256), 0, stream>>>(
        inQ, inK, inV, Wq, Wk, Wv, Wo,
        X16q, X16k, X16v, W16q, W16k, W16v, W16o);

    qkv_gemm_kernel<<<dim3(EE / 128, SS / 128, 3), dim3(256), 0, stream>>>(
        X16q, X16k, X16v, W16q, W16k, W16v, Qf, Kf, Vf);

    attn_mfma_kernel<<<dim3((SS / 64) * HH), dim3(256), 0, stream>>>(Qf, Kf, Vf, ctx);

    out_gemm_kernel<<<dim3(EE / 128, SS / 128), dim3(256), 0, stream>>>(ctx, W16o, out);
}

// Round 6
// 281.825 us; speedup vs baseline: 4.1544x; 1.1618x over previous
//
#include <hip/hip_runtime.h>

// Problem constants: B=1, S=4096, E=768, H=12, D=64
#define SS 4096
#define EE 768
#define HH 12
#define DD 64

typedef __attribute__((ext_vector_type(4))) float f32x4;
typedef __attribute__((ext_vector_type(8))) _Float16 f16x8;
typedef __attribute__((ext_vector_type(4))) _Float16 f16x4;
typedef __attribute__((ext_vector_type(8))) unsigned short u16x8;

// ---------------- cast fp32 -> f16 (Wq pre-scaled by 1/sqrt(D)) ------------
__global__ __launch_bounds__(256) void cast_kernel(
    const float* __restrict__ xq, const float* __restrict__ xk,
    const float* __restrict__ xv, const float* __restrict__ wq,
    const float* __restrict__ wk, const float* __restrict__ wv,
    const float* __restrict__ wo, _Float16* __restrict__ oxq,
    _Float16* __restrict__ oxk, _Float16* __restrict__ oxv,
    _Float16* __restrict__ owq, _Float16* __restrict__ owk,
    _Float16* __restrict__ owv, _Float16* __restrict__ owo) {
    const int seg = blockIdx.y;
    const float* src;
    _Float16* dst;
    int n;
    float s = 1.0f;
    switch (seg) {
        case 0: src = xq; dst = oxq; n = SS * EE; break;
        case 1: src = xk; dst = oxk; n = SS * EE; break;
        case 2: src = xv; dst = oxv; n = SS * EE; break;
        case 3: src = wq; dst = owq; n = EE * EE; s = 0.125f; break;
        case 4: src = wk; dst = owk; n = EE * EE; break;
        case 5: src = wv; dst = owv; n = EE * EE; break;
        default: src = wo; dst = owo; n = EE * EE; break;
    }
    const int i = (blockIdx.x * 256 + threadIdx.x) * 4;
    if (i < n) {
        const float4 v = *(const float4*)(src + i);
        f16x4 o;
        o[0] = (_Float16)(v.x * s); o[1] = (_Float16)(v.y * s);
        o[2] = (_Float16)(v.z * s); o[3] = (_Float16)(v.w * s);
        *(f16x4*)(dst + i) = o;
    }
}

// ---------------- f16 MFMA GEMM (m97 structure, unchanged) ------------------
template <bool F32OUT>
__device__ __forceinline__ void gemm_f16_body(const _Float16* __restrict__ A,
                                              const _Float16* __restrict__ B,
                                              void* __restrict__ Yv) {
    __shared__ _Float16 As[128 * 32];
    __shared__ _Float16 Bs[128 * 32];

    const int tid = threadIdx.x;
    const int w = tid >> 6, lane = tid & 63;
    const int g = lane >> 4, c = lane & 15;
    const int wr = (w >> 1) * 64, wc = (w & 1) * 64;
    const int m0 = blockIdx.y * 128, n0 = blockIdx.x * 128;

    f32x4 acc[4][4] = {};

    for (int k0 = 0; k0 < EE; k0 += 32) {
        __syncthreads();
#pragma unroll
        for (int i = 0; i < 2; ++i) {
            const int ca = tid + i * 256;
            __builtin_amdgcn_global_load_lds(
                (const __attribute__((address_space(1))) void*)(
                    A + (size_t)(m0 + (ca >> 2)) * EE + k0 + (ca & 3) * 8),
                (__attribute__((address_space(3))) void*)(As + ca * 8), 16, 0, 0);
            __builtin_amdgcn_global_load_lds(
                (const __attribute__((address_space(1))) void*)(
                    B + (size_t)(n0 + (ca >> 2)) * EE + k0 + (ca & 3) * 8),
                (__attribute__((address_space(3))) void*)(Bs + ca * 8), 16, 0, 0);
        }
        __syncthreads();

        f16x8 af[4], bf[4];
#pragma unroll
        for (int t = 0; t < 4; ++t) {
            af[t] = *(const f16x8*)(As + (wr + t * 16 + c) * 32 + g * 8);
            bf[t] = *(const f16x8*)(Bs + (wc + t * 16 + c) * 32 + g * 8);
        }
#pragma unroll
        for (int mt = 0; mt < 4; ++mt)
#pragma unroll
            for (int nt = 0; nt < 4; ++nt)
                acc[mt][nt] = __builtin_amdgcn_mfma_f32_16x16x32_f16(
                    af[mt], bf[nt], acc[mt][nt], 0, 0, 0);
    }

    if (F32OUT) {
        float* Y = (float*)Yv;
#pragma unroll
        for (int mt = 0; mt < 4; ++mt)
#pragma unroll
            for (int nt = 0; nt < 4; ++nt)
#pragma unroll
                for (int r = 0; r < 4; ++r)
                    Y[(size_t)(m0 + wr + mt * 16 + g * 4 + r) * EE +
                      n0 + wc + nt * 16 + c] = acc[mt][nt][r];
    } else {
        _Float16* Y = (_Float16*)Yv;
#pragma unroll
        for (int mt = 0; mt < 4; ++mt)
#pragma unroll
            for (int nt = 0; nt < 4; ++nt)
#pragma unroll
                for (int r = 0; r < 4; ++r)
                    Y[(size_t)(m0 + wr + mt * 16 + g * 4 + r) * EE +
                      n0 + wc + nt * 16 + c] = (_Float16)acc[mt][nt][r];
    }
}

__global__ __launch_bounds__(256) void qkv_gemm_kernel(
    const _Float16* __restrict__ Xq, const _Float16* __restrict__ Xk,
    const _Float16* __restrict__ Xv, const _Float16* __restrict__ Wq,
    const _Float16* __restrict__ Wk, const _Float16* __restrict__ Wv,
    _Float16* __restrict__ Yq, _Float16* __restrict__ Yk,
    _Float16* __restrict__ Yv) {
    const int z = blockIdx.z;
    const _Float16* X = (z == 0) ? Xq : (z == 1) ? Xk : Xv;
    const _Float16* W = (z == 0) ? Wq : (z == 1) ? Wk : Wv;
    _Float16* Y = (z == 0) ? Yq : (z == 1) ? Yk : Yv;
    gemm_f16_body<false>(X, W, (void*)Y);
}

__global__ __launch_bounds__(256) void out_gemm_kernel(
    const _Float16* __restrict__ X, const _Float16* __restrict__ W,
    float* __restrict__ Y) {
    gemm_f16_body<true>(X, W, (void*)Y);
}

// ---------------- Flash attention v2: swapped QK^T, P-in-register ----------
// 128 threads = 2 waves; each wave owns 32 q-rows; KV tiles of 64 rows.
// Swapped QK^T: S^T[kv][q] = mfma(A=K, B=Q^T) -> lane (g,c) holds
//   sc[nt][r] = S[q = c][kv = 16*nt + 4*g + r]  (one q-row per lane!)
// V stored kv-permuted: LDS pos sigma(kv) = 32*(nt>>1) + 8*g + 4*(nt&1) + r
//   => PV B-frag slot (ks, j) needs p[nt=2*ks+(j>>2)][r=j&3] -- lane-local.
// K staged via global_load_lds, source-preswizzled (chunk ^= row&7).
__global__ __launch_bounds__(128) void attn_mfma_kernel(
    const _Float16* __restrict__ Qf, const _Float16* __restrict__ Kf,
    const _Float16* __restrict__ Vf, _Float16* __restrict__ C) {
    __shared__ _Float16 Ks[2][64 * 64];        // linear [row][64 d], swizzled
    __shared__ unsigned char VtB[2][64 * 144]; // Vt[d][pos], 144 B rows

    const int tid = threadIdx.x;
    const int bid = blockIdx.x;
    const int sw = (bid & 7) * 96 + (bid >> 3);  // XCD swizzle (768 = 8*96)
    const int h = sw >> 6;
    const int q0 = (sw & 63) * 64;
    const int w = tid >> 6;
    const int lane = tid & 63;
    const int g = lane >> 4;
    const int c = lane & 15;

    const int vr2 = tid >> 3;   // 0..15
    const int vm = tid & 7;     // d-chunk for V staging

    // Q fragments (pre-scaled by 1/sqrt(D) in Wq): qa[qf][ks]
    f16x8 qa[2][2];
#pragma unroll
    for (int qf = 0; qf < 2; ++qf) {
        const _Float16* qp =
            Qf + (size_t)(q0 + w * 32 + qf * 16 + c) * EE + h * DD + g * 8;
        qa[qf][0] = *(const f16x8*)(qp);
        qa[qf][1] = *(const f16x8*)(qp + 32);
    }

    f32x4 o[2][4] = {};  // o[qf][dt][r] = O[q][d = 16*dt + 4*g + r]
    float m_q[2] = {-1e30f, -1e30f}, l_q[2] = {0.0f, 0.0f};
    u16x8 vreg[2][2];

    // --- staging helpers ---
#define ISSUE_K(buf, t0k)                                                     \
    {                                                                          \
        _Pragma("unroll") for (int i = 0; i < 4; ++i) {                        \
            const int L = i * 128 + tid;                                       \
            const int r_ = L >> 3;                                             \
            const int cc_ = (L & 7) ^ (r_ & 7);                                \
            __builtin_amdgcn_global_load_lds(                                  \
                (const __attribute__((address_space(1))) void*)(               \
                    Kf + (size_t)((t0k) + r_) * EE + h * DD + cc_ * 8),        \
                (__attribute__((address_space(3))) void*)(&Ks[buf][L * 8]),    \
                16, 0, 0);                                                     \
        }                                                                      \
    }
#define LOAD_V(t0v)                                                           \
    {                                                                          \
        _Pragma("unroll") for (int u = 0; u < 2; ++u) {                        \
            const int vrr = vr2 + 16 * u;                                      \
            const unsigned short* vp = (const unsigned short*)(                \
                Vf + (size_t)((t0v) + 2 * vrr) * EE + h * DD + vm * 8);        \
            vreg[u][0] = *(const u16x8*)(vp);                                  \
            vreg[u][1] = *(const u16x8*)(vp + EE);                             \
        }                                                                      \
    }
#define WRITE_V(buf)                                                          \
    {                                                                          \
        _Pragma("unroll") for (int u = 0; u < 2; ++u) {                        \
            const int vrr = vr2 + 16 * u;                                      \
            const int pu = 16 * (vrr >> 4) + 4 * ((vrr >> 1) & 3) +            \
                           2 * ((vrr >> 3) & 1) + (vrr & 1);                   \
            _Pragma("unroll") for (int j = 0; j < 8; ++j) {                    \
                const int d_ = vm * 8 + j;                                     \
                const unsigned off =                                           \
                    (unsigned)(144 * d_ + 4 * pu) ^ (unsigned)(vm << 4);       \
                *(unsigned int*)(&VtB[buf][off]) =                             \
                    (unsigned)vreg[u][0][j] | ((unsigned)vreg[u][1][j] << 16); \
            }                                                                  \
        }                                                                      \
    }

    // prologue: stage tile 0 into buf 0
    ISSUE_K(0, 0);
    LOAD_V(0);
    WRITE_V(0);
    __syncthreads();

    for (int t = 0; t < SS / 64; ++t) {
        const int cur = t & 1;
        if (t < SS / 64 - 1) {
            ISSUE_K(cur ^ 1, (t + 1) * 64);
            LOAD_V((t + 1) * 64);
        }

        // --- QK^T (swapped): sc[qf][nt] ---
        f32x4 sc[2][4] = {};
        __builtin_amdgcn_s_setprio(1);
#pragma unroll
        for (int ks = 0; ks < 2; ++ks) {
#pragma unroll
            for (int nt = 0; nt < 4; ++nt) {
                const f16x8 kbv = *(const f16x8*)(
                    &Ks[cur][(16 * nt + c) * 64 + (((g + 4 * ks) ^ (c & 7)) * 8)]);
#pragma unroll
                for (int qf = 0; qf < 2; ++qf)
                    sc[qf][nt] = __builtin_amdgcn_mfma_f32_16x16x32_f16(
                        kbv, qa[qf][ks], sc[qf][nt], 0, 0, 0);
            }
        }
        __builtin_amdgcn_s_setprio(0);

        // --- online softmax (one q-row per lane per qf) ---
        f16x8 pb[2][2];
#pragma unroll
        for (int qf = 0; qf < 2; ++qf) {
            float mx0 = fmaxf(fmaxf(sc[qf][0][0], sc[qf][0][1]),
                              fmaxf(sc[qf][0][2], sc[qf][0][3]));
            float mx1 = fmaxf(fmaxf(sc[qf][1][0], sc[qf][1][1]),
                              fmaxf(sc[qf][1][2], sc[qf][1][3]));
            float mx2 = fmaxf(fmaxf(sc[qf][2][0], sc[qf][2][1]),
                              fmaxf(sc[qf][2][2], sc[qf][2][3]));
            float mx3 = fmaxf(fmaxf(sc[qf][3][0], sc[qf][3][1]),
                              fmaxf(sc[qf][3][2], sc[qf][3][3]));
            float mx = fmaxf(fmaxf(mx0, mx1), fmaxf(mx2, mx3));
            mx = fmaxf(mx, __shfl_xor(mx, 16));
            mx = fmaxf(mx, __shfl_xor(mx, 32));
            const float mnew = fmaxf(m_q[qf], mx);
            const float corr = __expf(m_q[qf] - mnew);
            m_q[qf] = mnew;
            float p[4][4];
            float rs = 0.0f;
#pragma unroll
            for (int nt = 0; nt < 4; ++nt)
#pragma unroll
                for (int r = 0; r < 4; ++r) {
                    p[nt][r] = __expf(sc[qf][nt][r] - mnew);
                    rs += p[nt][r];
                }
            rs += __shfl_xor(rs, 16);
            rs += __shfl_xor(rs, 32);
            l_q[qf] = l_q[qf] * corr + rs;
#pragma unroll
            for (int ks = 0; ks < 2; ++ks) {
                f16x8 t8;
                t8[0] = (_Float16)p[2 * ks][0];
                t8[1] = (_Float16)p[2 * ks][1];
                t8[2] = (_Float16)p[2 * ks][2];
                t8[3] = (_Float16)p[2 * ks][3];
                t8[4] = (_Float16)p[2 * ks + 1][0];
                t8[5] = (_Float16)p[2 * ks + 1][1];
                t8[6] = (_Float16)p[2 * ks + 1][2];
                t8[7] = (_Float16)p[2 * ks + 1][3];
                pb[qf][ks] = t8;
            }
#pragma unroll
            for (int dt = 0; dt < 4; ++dt)
                o[qf][dt] *= corr;
        }

        // --- PV: O^T[d][q] += V^T[d][kv] * P^T[kv][q] ---
        __builtin_amdgcn_s_setprio(1);
#pragma unroll
        for (int ks = 0; ks < 2; ++ks) {
#pragma unroll
            for (int dt = 0; dt < 4; ++dt) {
                const int d = 16 * dt + c;
                const unsigned off = (unsigned)(144 * d + 64 * ks + 16 * g) ^
                                     ((unsigned)((d >> 3) & 7) << 4);
                const f16x8 va = *(const f16x8*)(&VtB[cur][off]);
#pragma unroll
                for (int qf = 0; qf < 2; ++qf)
                    o[qf][dt] = __builtin_amdgcn_mfma_f32_16x16x32_f16(
                        va, pb[qf][ks], o[qf][dt], 0, 0, 0);
            }
        }
        __builtin_amdgcn_s_setprio(0);

        if (t < SS / 64 - 1) WRITE_V(cur ^ 1);
        __syncthreads();
    }

    // --- epilogue: O[q][d] = o[qf][dt][r] / l ---
#pragma unroll
    for (int qf = 0; qf < 2; ++qf) {
        const float inv = 1.0f / l_q[qf];
        _Float16* cp = C + (size_t)(q0 + w * 32 + qf * 16 + c) * EE + h * DD;
#pragma unroll
        for (int dt = 0; dt < 4; ++dt) {
            f16x4 ov;
            ov[0] = (_Float16)(o[qf][dt][0] * inv);
            ov[1] = (_Float16)(o[qf][dt][1] * inv);
            ov[2] = (_Float16)(o[qf][dt][2] * inv);
            ov[3] = (_Float16)(o[qf][dt][3] * inv);
            *(f16x4*)(cp + 16 * dt + 4 * g) = ov;
        }
    }
#undef ISSUE_K
#undef LOAD_V
#undef WRITE_V
}

// ---------------- launch ----------------------------------------------------
extern "C" void kernel_launch(void* const* d_in, const int* in_sizes, int n_in,
                              void* d_out, int out_size, void* d_ws, size_t ws_size,
                              hipStream_t stream) {
    const float* inQ = (const float*)d_in[0];
    const float* inK = (const float*)d_in[1];
    const float* inV = (const float*)d_in[2];
    const float* Wq = (const float*)d_in[3];
    const float* Wk = (const float*)d_in[4];
    const float* Wv = (const float*)d_in[5];
    const float* Wo = (const float*)d_in[6];
    float* out = (float*)d_out;

    const size_t SE = (size_t)SS * EE, E2 = (size_t)EE * EE;
    _Float16* p = (_Float16*)d_ws;
    _Float16* X16q = p; p += SE;
    _Float16* X16k = p; p += SE;
    _Float16* X16v = p; p += SE;
    _Float16* W16q = p; p += E2;
    _Float16* W16k = p; p += E2;
    _Float16* W16v = p; p += E2;
    _Float16* W16o = p; p += E2;
    _Float16* Qf = p; p += SE;
    _Float16* Kf = p; p += SE;
    _Float16* Vf = p; p += SE;
    _Float16* ctx = p; p += SE;

    cast_kernel<<<dim3(SS * EE / 1024, 7), dim3(256), 0, stream>>>(
        inQ, inK, inV, Wq, Wk, Wv, Wo,
        X16q, X16k, X16v, W16q, W16k, W16v, W16o);

    qkv_gemm_kernel<<<dim3(EE / 128, SS / 128, 3), dim3(256), 0, stream>>>(
        X16q, X16k, X16v, W16q, W16k, W16v, Qf, Kf, Vf);

    attn_mfma_kernel<<<dim3((SS / 64) * HH), dim3(128), 0, stream>>>(Qf, Kf, Vf, ctx);

    out_gemm_kernel<<<dim3(EE / 128, SS / 128), dim3(256), 0, stream>>>(ctx, W16o, out);
}

// Round 8
// 253.918 us; speedup vs baseline: 4.6111x; 1.1099x over previous
//
#include <hip/hip_runtime.h>

// Problem constants: B=1, S=4096, E=768, H=12, D=64
#define SS 4096
#define EE 768
#define HH 12
#define DD 64

typedef __attribute__((ext_vector_type(4))) float f32x4;
typedef __attribute__((ext_vector_type(8))) _Float16 f16x8;
typedef __attribute__((ext_vector_type(4))) _Float16 f16x4;
typedef __attribute__((ext_vector_type(8))) unsigned short u16x8;

// ---------------- cast fp32 -> f16 (Wq pre-scaled by 1/sqrt(D)) ------------
__global__ __launch_bounds__(256) void cast_kernel(
    const float* __restrict__ xq, const float* __restrict__ xk,
    const float* __restrict__ xv, const float* __restrict__ wq,
    const float* __restrict__ wk, const float* __restrict__ wv,
    const float* __restrict__ wo, _Float16* __restrict__ oxq,
    _Float16* __restrict__ oxk, _Float16* __restrict__ oxv,
    _Float16* __restrict__ owq, _Float16* __restrict__ owk,
    _Float16* __restrict__ owv, _Float16* __restrict__ owo) {
    const int seg = blockIdx.y;
    const float* src;
    _Float16* dst;
    int n;
    float s = 1.0f;
    switch (seg) {
        case 0: src = xq; dst = oxq; n = SS * EE; break;
        case 1: src = xk; dst = oxk; n = SS * EE; break;
        case 2: src = xv; dst = oxv; n = SS * EE; break;
        case 3: src = wq; dst = owq; n = EE * EE; s = 0.125f; break;
        case 4: src = wk; dst = owk; n = EE * EE; break;
        case 5: src = wv; dst = owv; n = EE * EE; break;
        default: src = wo; dst = owo; n = EE * EE; break;
    }
    const int i = (blockIdx.x * 256 + threadIdx.x) * 4;
    if (i < n) {
        const float4 v = *(const float4*)(src + i);
        f16x4 o;
        o[0] = (_Float16)(v.x * s); o[1] = (_Float16)(v.y * s);
        o[2] = (_Float16)(v.z * s); o[3] = (_Float16)(v.w * s);
        *(f16x4*)(dst + i) = o;
    }
}

// ---------------- f16 MFMA GEMM (m97 structure, unchanged) ------------------
template <bool F32OUT>
__device__ __forceinline__ void gemm_f16_body(const _Float16* __restrict__ A,
                                              const _Float16* __restrict__ B,
                                              void* __restrict__ Yv) {
    __shared__ _Float16 As[128 * 32];
    __shared__ _Float16 Bs[128 * 32];

    const int tid = threadIdx.x;
    const int w = tid >> 6, lane = tid & 63;
    const int g = lane >> 4, c = lane & 15;
    const int wr = (w >> 1) * 64, wc = (w & 1) * 64;
    const int m0 = blockIdx.y * 128, n0 = blockIdx.x * 128;

    f32x4 acc[4][4] = {};

    for (int k0 = 0; k0 < EE; k0 += 32) {
        __syncthreads();
#pragma unroll
        for (int i = 0; i < 2; ++i) {
            const int ca = tid + i * 256;
            __builtin_amdgcn_global_load_lds(
                (const __attribute__((address_space(1))) void*)(
                    A + (size_t)(m0 + (ca >> 2)) * EE + k0 + (ca & 3) * 8),
                (__attribute__((address_space(3))) void*)(As + ca * 8), 16, 0, 0);
            __builtin_amdgcn_global_load_lds(
                (const __attribute__((address_space(1))) void*)(
                    B + (size_t)(n0 + (ca >> 2)) * EE + k0 + (ca & 3) * 8),
                (__attribute__((address_space(3))) void*)(Bs + ca * 8), 16, 0, 0);
        }
        __syncthreads();

        f16x8 af[4], bf[4];
#pragma unroll
        for (int t = 0; t < 4; ++t) {
            af[t] = *(const f16x8*)(As + (wr + t * 16 + c) * 32 + g * 8);
            bf[t] = *(const f16x8*)(Bs + (wc + t * 16 + c) * 32 + g * 8);
        }
#pragma unroll
        for (int mt = 0; mt < 4; ++mt)
#pragma unroll
            for (int nt = 0; nt < 4; ++nt)
                acc[mt][nt] = __builtin_amdgcn_mfma_f32_16x16x32_f16(
                    af[mt], bf[nt], acc[mt][nt], 0, 0, 0);
    }

    if (F32OUT) {
        float* Y = (float*)Yv;
#pragma unroll
        for (int mt = 0; mt < 4; ++mt)
#pragma unroll
            for (int nt = 0; nt < 4; ++nt)
#pragma unroll
                for (int r = 0; r < 4; ++r)
                    Y[(size_t)(m0 + wr + mt * 16 + g * 4 + r) * EE +
                      n0 + wc + nt * 16 + c] = acc[mt][nt][r];
    } else {
        _Float16* Y = (_Float16*)Yv;
#pragma unroll
        for (int mt = 0; mt < 4; ++mt)
#pragma unroll
            for (int nt = 0; nt < 4; ++nt)
#pragma unroll
                for (int r = 0; r < 4; ++r)
                    Y[(size_t)(m0 + wr + mt * 16 + g * 4 + r) * EE +
                      n0 + wc + nt * 16 + c] = (_Float16)acc[mt][nt][r];
    }
}

__global__ __launch_bounds__(256) void qkv_gemm_kernel(
    const _Float16* __restrict__ Xq, const _Float16* __restrict__ Xk,
    const _Float16* __restrict__ Xv, const _Float16* __restrict__ Wq,
    const _Float16* __restrict__ Wk, const _Float16* __restrict__ Wv,
    _Float16* __restrict__ Yq, _Float16* __restrict__ Yk,
    _Float16* __restrict__ Yv) {
    const int z = blockIdx.z;
    const _Float16* X = (z == 0) ? Xq : (z == 1) ? Xk : Xv;
    const _Float16* W = (z == 0) ? Wq : (z == 1) ? Wk : Wv;
    _Float16* Y = (z == 0) ? Yq : (z == 1) ? Yk : Yv;
    gemm_f16_body<false>(X, W, (void*)Y);
}

__global__ __launch_bounds__(256) void out_gemm_kernel(
    const _Float16* __restrict__ X, const _Float16* __restrict__ W,
    float* __restrict__ Y) {
    gemm_f16_body<true>(X, W, (void*)Y);
}

// ---------------- Flash attention v3: 4 waves x 16 q-rows ------------------
// 256 threads = 4 waves; wave w owns q-rows [q0+16w, q0+16w+16).
// Same swapped-QK^T / P-in-register / permuted-V / preswizzled-K structure as
// v2, but 2x the waves per CU (12 vs 6) to attack the latency stall seen in
// round 6 (occupancy 15.7%, ~70% idle). K/V LDS reads duplicate 2x (we're
// stall-bound, not DS-bound). T13 defer-max skips the O-rescale when the
// running max grew by <= 8 (P <= e^8 fits f16).
__global__ __launch_bounds__(256) void attn_mfma_kernel(
    const _Float16* __restrict__ Qf, const _Float16* __restrict__ Kf,
    const _Float16* __restrict__ Vf, _Float16* __restrict__ C) {
    __shared__ _Float16 Ks[2][64 * 64];        // linear [row][64 d], swizzled
    __shared__ unsigned char VtB[2][64 * 144]; // Vt[d][pos], 144 B rows

    const int tid = threadIdx.x;
    const int bid = blockIdx.x;
    const int sw = (bid & 7) * 96 + (bid >> 3);  // XCD swizzle (768 = 8*96)
    const int h = sw >> 6;
    const int q0 = (sw & 63) * 64;
    const int w = tid >> 6;
    const int lane = tid & 63;
    const int g = lane >> 4;
    const int c = lane & 15;

    const int vrr = tid >> 3;   // 0..31: V row-pair (2vrr, 2vrr+1)
    const int vm = tid & 7;     // d-chunk for V staging

    // Q fragments (pre-scaled by 1/sqrt(D) in Wq)
    f16x8 qa[2];
    {
        const _Float16* qp =
            Qf + (size_t)(q0 + w * 16 + c) * EE + h * DD + g * 8;
        qa[0] = *(const f16x8*)(qp);
        qa[1] = *(const f16x8*)(qp + 32);
    }

    f32x4 o[4] = {};  // o[dt][r] = O[q][d = 16*dt + 4*g + r]
    float m_q = -1e30f, l_q = 0.0f;
    u16x8 vreg[2];

    // --- staging helpers (256 threads) ---
#define ISSUE_K(buf, t0k)                                                     \
    {                                                                          \
        _Pragma("unroll") for (int i = 0; i < 2; ++i) {                        \
            const int L = i * 256 + tid;                                       \
            const int r_ = L >> 3;                                             \
            const int cc_ = (L & 7) ^ (r_ & 7);                                \
            __builtin_amdgcn_global_load_lds(                                  \
                (const __attribute__((address_space(1))) void*)(               \
                    Kf + (size_t)((t0k) + r_) * EE + h * DD + cc_ * 8),        \
                (__attribute__((address_space(3))) void*)(&Ks[buf][L * 8]),    \
                16, 0, 0);                                                     \
        }                                                                      \
    }
#define LOAD_V(t0v)                                                           \
    {                                                                          \
        const unsigned short* vp = (const unsigned short*)(                    \
            Vf + (size_t)((t0v) + 2 * vrr) * EE + h * DD + vm * 8);            \
        vreg[0] = *(const u16x8*)(vp);                                         \
        vreg[1] = *(const u16x8*)(vp + EE);                                    \
    }
#define WRITE_V(buf)                                                          \
    {                                                                          \
        const int pu = 16 * (vrr >> 4) + 4 * ((vrr >> 1) & 3) +                \
                       2 * ((vrr >> 3) & 1) + (vrr & 1);                       \
        _Pragma("unroll") for (int j = 0; j < 8; ++j) {                        \
            const int d_ = vm * 8 + j;                                         \
            const unsigned off =                                               \
                (unsigned)(144 * d_ + 4 * pu) ^ (unsigned)(vm << 4);           \
            *(unsigned int*)(&VtB[buf][off]) =                                 \
                (unsigned)vreg[0][j] | ((unsigned)vreg[1][j] << 16);           \
        }                                                                      \
    }

    // prologue: stage tile 0 into buf 0
    ISSUE_K(0, 0);
    LOAD_V(0);
    WRITE_V(0);
    __syncthreads();

    for (int t = 0; t < SS / 64; ++t) {
        const int cur = t & 1;
        if (t < SS / 64 - 1) {
            ISSUE_K(cur ^ 1, (t + 1) * 64);
            LOAD_V((t + 1) * 64);
        }

        // --- QK^T (swapped): sc[nt][r] = S[q=c][kv=16nt+4g+r] ---
        f32x4 sc[4] = {};
        __builtin_amdgcn_s_setprio(1);
#pragma unroll
        for (int ks = 0; ks < 2; ++ks) {
#pragma unroll
            for (int nt = 0; nt < 4; ++nt) {
                const f16x8 kbv = *(const f16x8*)(
                    &Ks[cur][(16 * nt + c) * 64 + (((g + 4 * ks) ^ (c & 7)) * 8)]);
                sc[nt] = __builtin_amdgcn_mfma_f32_16x16x32_f16(
                    kbv, qa[ks], sc[nt], 0, 0, 0);
            }
        }
        __builtin_amdgcn_s_setprio(0);

        // --- online softmax (one q-row per lane), T13 defer-max ---
        f16x8 pb[2];
        {
            float mx0 = fmaxf(fmaxf(sc[0][0], sc[0][1]), fmaxf(sc[0][2], sc[0][3]));
            float mx1 = fmaxf(fmaxf(sc[1][0], sc[1][1]), fmaxf(sc[1][2], sc[1][3]));
            float mx2 = fmaxf(fmaxf(sc[2][0], sc[2][1]), fmaxf(sc[2][2], sc[2][3]));
            float mx3 = fmaxf(fmaxf(sc[3][0], sc[3][1]), fmaxf(sc[3][2], sc[3][3]));
            float mx = fmaxf(fmaxf(mx0, mx1), fmaxf(mx2, mx3));
            mx = fmaxf(mx, __shfl_xor(mx, 16));
            mx = fmaxf(mx, __shfl_xor(mx, 32));
            if (!__all(mx - m_q <= 8.0f)) {
                const float mnew = fmaxf(m_q, mx);
                const float corr = __expf(m_q - mnew);
                m_q = mnew;
                l_q *= corr;
#pragma unroll
                for (int dt = 0; dt < 4; ++dt)
                    o[dt] *= corr;
            }
            float p[4][4];
            float rs = 0.0f;
#pragma unroll
            for (int nt = 0; nt < 4; ++nt)
#pragma unroll
                for (int r = 0; r < 4; ++r) {
                    p[nt][r] = __expf(sc[nt][r] - m_q);
                    rs += p[nt][r];
                }
            rs += __shfl_xor(rs, 16);
            rs += __shfl_xor(rs, 32);
            l_q += rs;
#pragma unroll
            for (int ks = 0; ks < 2; ++ks) {
                f16x8 t8;
                t8[0] = (_Float16)p[2 * ks][0];
                t8[1] = (_Float16)p[2 * ks][1];
                t8[2] = (_Float16)p[2 * ks][2];
                t8[3] = (_Float16)p[2 * ks][3];
                t8[4] = (_Float16)p[2 * ks + 1][0];
                t8[5] = (_Float16)p[2 * ks + 1][1];
                t8[6] = (_Float16)p[2 * ks + 1][2];
                t8[7] = (_Float16)p[2 * ks + 1][3];
                pb[ks] = t8;
            }
        }

        // --- PV: O^T[d][q] += V^T[d][kv] * P^T[kv][q] ---
        __builtin_amdgcn_s_setprio(1);
#pragma unroll
        for (int ks = 0; ks < 2; ++ks) {
#pragma unroll
            for (int dt = 0; dt < 4; ++dt) {
                const int d = 16 * dt + c;
                const unsigned off = (unsigned)(144 * d + 64 * ks + 16 * g) ^
                                     ((unsigned)((d >> 3) & 7) << 4);
                const f16x8 va = *(const f16x8*)(&VtB[cur][off]);
                o[dt] = __builtin_amdgcn_mfma_f32_16x16x32_f16(
                    va, pb[ks], o[dt], 0, 0, 0);
            }
        }
        __builtin_amdgcn_s_setprio(0);

        if (t < SS / 64 - 1) WRITE_V(cur ^ 1);
        __syncthreads();
    }

    // --- epilogue: O[q][d] = o[dt][r] / l ---
    {
        const float inv = 1.0f / l_q;
        _Float16* cp = C + (size_t)(q0 + w * 16 + c) * EE + h * DD;
#pragma unroll
        for (int dt = 0; dt < 4; ++dt) {
            f16x4 ov;
            ov[0] = (_Float16)(o[dt][0] * inv);
            ov[1] = (_Float16)(o[dt][1] * inv);
            ov[2] = (_Float16)(o[dt][2] * inv);
            ov[3] = (_Float16)(o[dt][3] * inv);
            *(f16x4*)(cp + 16 * dt + 4 * g) = ov;
        }
    }
#undef ISSUE_K
#undef LOAD_V
#undef WRITE_V
}

// ---------------- launch ----------------------------------------------------
extern "C" void kernel_launch(void* const* d_in, const int* in_sizes, int n_in,
                              void* d_out, int out_size, void* d_ws, size_t ws_size,
                              hipStream_t stream) {
    const float* inQ = (const float*)d_in[0];
    const float* inK = (const float*)d_in[1];
    const float* inV = (const float*)d_in[2];
    const float* Wq = (const float*)d_in[3];
    const float* Wk = (const float*)d_in[4];
    const float* Wv = (const float*)d_in[5];
    const float* Wo = (const float*)d_in[6];
    float* out = (float*)d_out;

    const size_t SE = (size_t)SS * EE, E2 = (size_t)EE * EE;
    _Float16* p = (_Float16*)d_ws;
    _Float16* X16q = p; p += SE;
    _Float16* X16k = p; p += SE;
    _Float16* X16v = p; p += SE;
    _Float16* W16q = p; p += E2;
    _Float16* W16k = p; p += E2;
    _Float16* W16v = p; p += E2;
    _Float16* W16o = p; p += E2;
    _Float16* Qf = p; p += SE;
    _Float16* Kf = p; p += SE;
    _Float16* Vf = p; p += SE;
    _Float16* ctx = p; p += SE;

    cast_kernel<<<dim3(SS * EE / 1024, 7), dim3(256), 0, stream>>>(
        inQ, inK, inV, Wq, Wk, Wv, Wo,
        X16q, X16k, X16v, W16q, W16k, W16v, W16o);

    qkv_gemm_kernel<<<dim3(EE / 128, SS / 128, 3), dim3(256), 0, stream>>>(
        X16q, X16k, X16v, W16q, W16k, W16v, Qf, Kf, Vf);

    attn_mfma_kernel<<<dim3((SS / 64) * HH), dim3(256), 0, stream>>>(Qf, Kf, Vf, ctx);

    out_gemm_kernel<<<dim3(EE / 128, SS / 128), dim3(256), 0, stream>>>(ctx, W16o, out);
}

// Round 12
// 251.198 us; speedup vs baseline: 4.6610x; 1.0108x over previous
//
#include <hip/hip_runtime.h>

// Problem constants: B=1, S=4096, E=768, H=12, D=64
#define SS 4096
#define EE 768
#define HH 12
#define DD 64

typedef __attribute__((ext_vector_type(4))) float f32x4;
typedef __attribute__((ext_vector_type(8))) _Float16 f16x8;
typedef __attribute__((ext_vector_type(4))) _Float16 f16x4;
typedef __attribute__((ext_vector_type(8))) unsigned short u16x8;

// ---------------- cast fp32 -> f16 (Wq pre-scaled by 1/sqrt(D)) ------------
// 8 elems/thread: 2x float4 load -> 1x 16B f16x8 store (G13 sweet spot).
__global__ __launch_bounds__(256) void cast_kernel(
    const float* __restrict__ xq, const float* __restrict__ xk,
    const float* __restrict__ xv, const float* __restrict__ wq,
    const float* __restrict__ wk, const float* __restrict__ wv,
    const float* __restrict__ wo, _Float16* __restrict__ oxq,
    _Float16* __restrict__ oxk, _Float16* __restrict__ oxv,
    _Float16* __restrict__ owq, _Float16* __restrict__ owk,
    _Float16* __restrict__ owv, _Float16* __restrict__ owo) {
    const int seg = blockIdx.y;
    const float* src;
    _Float16* dst;
    int n;
    float s = 1.0f;
    switch (seg) {
        case 0: src = xq; dst = oxq; n = SS * EE; break;
        case 1: src = xk; dst = oxk; n = SS * EE; break;
        case 2: src = xv; dst = oxv; n = SS * EE; break;
        case 3: src = wq; dst = owq; n = EE * EE; s = 0.125f; break;
        case 4: src = wk; dst = owk; n = EE * EE; break;
        case 5: src = wv; dst = owv; n = EE * EE; break;
        default: src = wo; dst = owo; n = EE * EE; break;
    }
    const int i = (blockIdx.x * 256 + threadIdx.x) * 8;
    if (i < n) {
        const float4 v0 = *(const float4*)(src + i);
        const float4 v1 = *(const float4*)(src + i + 4);
        f16x8 o;
        o[0] = (_Float16)(v0.x * s); o[1] = (_Float16)(v0.y * s);
        o[2] = (_Float16)(v0.z * s); o[3] = (_Float16)(v0.w * s);
        o[4] = (_Float16)(v1.x * s); o[5] = (_Float16)(v1.y * s);
        o[6] = (_Float16)(v1.z * s); o[7] = (_Float16)(v1.w * s);
        *(f16x8*)(dst + i) = o;
    }
}

// ---------------- f16 MFMA GEMM (m97 structure, round-8 verified) -----------
template <bool F32OUT>
__device__ __forceinline__ void gemm_f16_body(const _Float16* __restrict__ A,
                                              const _Float16* __restrict__ B,
                                              void* __restrict__ Yv) {
    __shared__ _Float16 As[128 * 32];
    __shared__ _Float16 Bs[128 * 32];

    const int tid = threadIdx.x;
    const int w = tid >> 6, lane = tid & 63;
    const int g = lane >> 4, c = lane & 15;
    const int wr = (w >> 1) * 64, wc = (w & 1) * 64;
    const int m0 = blockIdx.y * 128, n0 = blockIdx.x * 128;

    f32x4 acc[4][4] = {};

    for (int k0 = 0; k0 < EE; k0 += 32) {
        __syncthreads();
#pragma unroll
        for (int i = 0; i < 2; ++i) {
            const int ca = tid + i * 256;
            __builtin_amdgcn_global_load_lds(
                (const __attribute__((address_space(1))) void*)(
                    A + (size_t)(m0 + (ca >> 2)) * EE + k0 + (ca & 3) * 8),
                (__attribute__((address_space(3))) void*)(As + ca * 8), 16, 0, 0);
            __builtin_amdgcn_global_load_lds(
                (const __attribute__((address_space(1))) void*)(
                    B + (size_t)(n0 + (ca >> 2)) * EE + k0 + (ca & 3) * 8),
                (__attribute__((address_space(3))) void*)(Bs + ca * 8), 16, 0, 0);
        }
        __syncthreads();

        f16x8 af[4], bf[4];
#pragma unroll
        for (int t = 0; t < 4; ++t) {
            af[t] = *(const f16x8*)(As + (wr + t * 16 + c) * 32 + g * 8);
            bf[t] = *(const f16x8*)(Bs + (wc + t * 16 + c) * 32 + g * 8);
        }
#pragma unroll
        for (int mt = 0; mt < 4; ++mt)
#pragma unroll
            for (int nt = 0; nt < 4; ++nt)
                acc[mt][nt] = __builtin_amdgcn_mfma_f32_16x16x32_f16(
                    af[mt], bf[nt], acc[mt][nt], 0, 0, 0);
    }

    if (F32OUT) {
        float* Y = (float*)Yv;
#pragma unroll
        for (int mt = 0; mt < 4; ++mt)
#pragma unroll
            for (int nt = 0; nt < 4; ++nt)
#pragma unroll
                for (int r = 0; r < 4; ++r)
                    Y[(size_t)(m0 + wr + mt * 16 + g * 4 + r) * EE +
                      n0 + wc + nt * 16 + c] = acc[mt][nt][r];
    } else {
        _Float16* Y = (_Float16*)Yv;
#pragma unroll
        for (int mt = 0; mt < 4; ++mt)
#pragma unroll
            for (int nt = 0; nt < 4; ++nt)
#pragma unroll
                for (int r = 0; r < 4; ++r)
                    Y[(size_t)(m0 + wr + mt * 16 + g * 4 + r) * EE +
                      n0 + wc + nt * 16 + c] = (_Float16)acc[mt][nt][r];
    }
}

__global__ __launch_bounds__(256) void qkv_gemm_kernel(
    const _Float16* __restrict__ Xq, const _Float16* __restrict__ Xk,
    const _Float16* __restrict__ Xv, const _Float16* __restrict__ Wq,
    const _Float16* __restrict__ Wk, const _Float16* __restrict__ Wv,
    _Float16* __restrict__ Yq, _Float16* __restrict__ Yk,
    _Float16* __restrict__ Yv) {
    const int z = blockIdx.z;
    const _Float16* X = (z == 0) ? Xq : (z == 1) ? Xk : Xv;
    const _Float16* W = (z == 0) ? Wq : (z == 1) ? Wk : Wv;
    _Float16* Y = (z == 0) ? Yq : (z == 1) ? Yk : Yv;
    gemm_f16_body<false>(X, W, (void*)Y);
}

__global__ __launch_bounds__(256) void out_gemm_kernel(
    const _Float16* __restrict__ X, const _Float16* __restrict__ W,
    float* __restrict__ Y) {
    gemm_f16_body<true>(X, W, (void*)Y);
}

// ---------------- Flash attention v3 (round-8 verified, unchanged) ----------
// 256 threads = 4 waves; wave w owns q-rows [q0+16w, q0+16w+16).
// Swapped QK^T / P-in-register / permuted-V / preswizzled-K; T13 defer-max.
__global__ __launch_bounds__(256) void attn_mfma_kernel(
    const _Float16* __restrict__ Qf, const _Float16* __restrict__ Kf,
    const _Float16* __restrict__ Vf, _Float16* __restrict__ C) {
    __shared__ _Float16 Ks[2][64 * 64];        // linear [row][64 d], swizzled
    __shared__ unsigned char VtB[2][64 * 144]; // Vt[d][pos], 144 B rows

    const int tid = threadIdx.x;
    const int bid = blockIdx.x;
    const int sw = (bid & 7) * 96 + (bid >> 3);  // XCD swizzle (768 = 8*96)
    const int h = sw >> 6;
    const int q0 = (sw & 63) * 64;
    const int w = tid >> 6;
    const int lane = tid & 63;
    const int g = lane >> 4;
    const int c = lane & 15;

    const int vrr = tid >> 3;   // 0..31: V row-pair (2vrr, 2vrr+1)
    const int vm = tid & 7;     // d-chunk for V staging

    f16x8 qa[2];
    {
        const _Float16* qp =
            Qf + (size_t)(q0 + w * 16 + c) * EE + h * DD + g * 8;
        qa[0] = *(const f16x8*)(qp);
        qa[1] = *(const f16x8*)(qp + 32);
    }

    f32x4 o[4] = {};  // o[dt][r] = O[q][d = 16*dt + 4*g + r]
    float m_q = -1e30f, l_q = 0.0f;
    u16x8 vreg[2];

#define ISSUE_K(buf, t0k)                                                     \
    {                                                                          \
        _Pragma("unroll") for (int i = 0; i < 2; ++i) {                        \
            const int L = i * 256 + tid;                                       \
            const int r_ = L >> 3;                                             \
            const int cc_ = (L & 7) ^ (r_ & 7);                                \
            __builtin_amdgcn_global_load_lds(                                  \
                (const __attribute__((address_space(1))) void*)(               \
                    Kf + (size_t)((t0k) + r_) * EE + h * DD + cc_ * 8),        \
                (__attribute__((address_space(3))) void*)(&Ks[buf][L * 8]),    \
                16, 0, 0);                                                     \
        }                                                                      \
    }
#define LOAD_V(t0v)                                                           \
    {                                                                          \
        const unsigned short* vp = (const unsigned short*)(                    \
            Vf + (size_t)((t0v) + 2 * vrr) * EE + h * DD + vm * 8);            \
        vreg[0] = *(const u16x8*)(vp);                                         \
        vreg[1] = *(const u16x8*)(vp + EE);                                    \
    }
#define WRITE_V(buf)                                                          \
    {                                                                          \
        const int pu = 16 * (vrr >> 4) + 4 * ((vrr >> 1) & 3) +                \
                       2 * ((vrr >> 3) & 1) + (vrr & 1);                       \
        _Pragma("unroll") for (int j = 0; j < 8; ++j) {                        \
            const int d_ = vm * 8 + j;                                         \
            const unsigned off =                                               \
                (unsigned)(144 * d_ + 4 * pu) ^ (unsigned)(vm << 4);           \
            *(unsigned int*)(&VtB[buf][off]) =                                 \
                (unsigned)vreg[0][j] | ((unsigned)vreg[1][j] << 16);           \
        }                                                                      \
    }

    ISSUE_K(0, 0);
    LOAD_V(0);
    WRITE_V(0);
    __syncthreads();

    for (int t = 0; t < SS / 64; ++t) {
        const int cur = t & 1;
        if (t < SS / 64 - 1) {
            ISSUE_K(cur ^ 1, (t + 1) * 64);
            LOAD_V((t + 1) * 64);
        }

        // --- QK^T (swapped): sc[nt][r] = S[q=c][kv=16nt+4g+r] ---
        f32x4 sc[4] = {};
        __builtin_amdgcn_s_setprio(1);
#pragma unroll
        for (int ks = 0; ks < 2; ++ks) {
#pragma unroll
            for (int nt = 0; nt < 4; ++nt) {
                const f16x8 kbv = *(const f16x8*)(
                    &Ks[cur][(16 * nt + c) * 64 + (((g + 4 * ks) ^ (c & 7)) * 8)]);
                sc[nt] = __builtin_amdgcn_mfma_f32_16x16x32_f16(
                    kbv, qa[ks], sc[nt], 0, 0, 0);
            }
        }
        __builtin_amdgcn_s_setprio(0);

        // --- online softmax (one q-row per lane), T13 defer-max ---
        f16x8 pb[2];
        {
            float mx0 = fmaxf(fmaxf(sc[0][0], sc[0][1]), fmaxf(sc[0][2], sc[0][3]));
            float mx1 = fmaxf(fmaxf(sc[1][0], sc[1][1]), fmaxf(sc[1][2], sc[1][3]));
            float mx2 = fmaxf(fmaxf(sc[2][0], sc[2][1]), fmaxf(sc[2][2], sc[2][3]));
            float mx3 = fmaxf(fmaxf(sc[3][0], sc[3][1]), fmaxf(sc[3][2], sc[3][3]));
            float mx = fmaxf(fmaxf(mx0, mx1), fmaxf(mx2, mx3));
            mx = fmaxf(mx, __shfl_xor(mx, 16));
            mx = fmaxf(mx, __shfl_xor(mx, 32));
            if (!__all(mx - m_q <= 8.0f)) {
                const float mnew = fmaxf(m_q, mx);
                const float corr = __expf(m_q - mnew);
                m_q = mnew;
                l_q *= corr;
#pragma unroll
                for (int dt = 0; dt < 4; ++dt)
                    o[dt] *= corr;
            }
            float p[4][4];
            float rs = 0.0f;
#pragma unroll
            for (int nt = 0; nt < 4; ++nt)
#pragma unroll
                for (int r = 0; r < 4; ++r) {
                    p[nt][r] = __expf(sc[nt][r] - m_q);
                    rs += p[nt][r];
                }
            rs += __shfl_xor(rs, 16);
            rs += __shfl_xor(rs, 32);
            l_q += rs;
#pragma unroll
            for (int ks = 0; ks < 2; ++ks) {
                f16x8 t8;
                t8[0] = (_Float16)p[2 * ks][0];
                t8[1] = (_Float16)p[2 * ks][1];
                t8[2] = (_Float16)p[2 * ks][2];
                t8[3] = (_Float16)p[2 * ks][3];
                t8[4] = (_Float16)p[2 * ks + 1][0];
                t8[5] = (_Float16)p[2 * ks + 1][1];
                t8[6] = (_Float16)p[2 * ks + 1][2];
                t8[7] = (_Float16)p[2 * ks + 1][3];
                pb[ks] = t8;
            }
        }

        // --- PV: O^T[d][q] += V^T[d][kv] * P^T[kv][q] ---
        __builtin_amdgcn_s_setprio(1);
#pragma unroll
        for (int ks = 0; ks < 2; ++ks) {
#pragma unroll
            for (int dt = 0; dt < 4; ++dt) {
                const int d = 16 * dt + c;
                const unsigned off = (unsigned)(144 * d + 64 * ks + 16 * g) ^
                                     ((unsigned)((d >> 3) & 7) << 4);
                const f16x8 va = *(const f16x8*)(&VtB[cur][off]);
                o[dt] = __builtin_amdgcn_mfma_f32_16x16x32_f16(
                    va, pb[ks], o[dt], 0, 0, 0);
            }
        }
        __builtin_amdgcn_s_setprio(0);

        if (t < SS / 64 - 1) WRITE_V(cur ^ 1);
        __syncthreads();
    }

    {
        const float inv = 1.0f / l_q;
        _Float16* cp = C + (size_t)(q0 + w * 16 + c) * EE + h * DD;
#pragma unroll
        for (int dt = 0; dt < 4; ++dt) {
            f16x4 ov;
            ov[0] = (_Float16)(o[dt][0] * inv);
            ov[1] = (_Float16)(o[dt][1] * inv);
            ov[2] = (_Float16)(o[dt][2] * inv);
            ov[3] = (_Float16)(o[dt][3] * inv);
            *(f16x4*)(cp + 16 * dt + 4 * g) = ov;
        }
    }
#undef ISSUE_K
#undef LOAD_V
#undef WRITE_V
}

// ---------------- launch ----------------------------------------------------
extern "C" void kernel_launch(void* const* d_in, const int* in_sizes, int n_in,
                              void* d_out, int out_size, void* d_ws, size_t ws_size,
                              hipStream_t stream) {
    const float* inQ = (const float*)d_in[0];
    const float* inK = (const float*)d_in[1];
    const float* inV = (const float*)d_in[2];
    const float* Wq = (const float*)d_in[3];
    const float* Wk = (const float*)d_in[4];
    const float* Wv = (const float*)d_in[5];
    const float* Wo = (const float*)d_in[6];
    float* out = (float*)d_out;

    const size_t SE = (size_t)SS * EE, E2 = (size_t)EE * EE;
    _Float16* p = (_Float16*)d_ws;
    _Float16* X16q = p; p += SE;
    _Float16* X16k = p; p += SE;
    _Float16* X16v = p; p += SE;
    _Float16* W16q = p; p += E2;
    _Float16* W16k = p; p += E2;
    _Float16* W16v = p; p += E2;
    _Float16* W16o = p; p += E2;
    _Float16* Qf = p; p += SE;
    _Float16* Kf = p; p += SE;
    _Float16* Vf = p; p += SE;
    _Float16* ctx = p; p += SE;

    // cast: 8 elems/thread -> grid.x = SS*EE/2048
    cast_kernel<<<dim3(SS * EE / 2048, 7), dim3(256), 0, stream>>>(
        inQ, inK, inV, Wq, Wk, Wv, Wo,
        X16q, X16k, X16v, W16q, W16k, W16v, W16o);

    qkv_gemm_kernel<<<dim3(EE / 128, SS / 128, 3), dim3(256), 0, stream>>>(
        X16q, X16k, X16v, W16q, W16k, W16v, Qf, Kf, Vf);

    attn_mfma_kernel<<<dim3((SS / 64) * HH), dim3(256), 0, stream>>>(Qf, Kf, Vf, ctx);

    out_gemm_kernel<<<dim3(EE / 128, SS / 128), dim3(256), 0, stream>>>(ctx, W16o, out);
}